// Round 5
// baseline (110.858 us; speedup 1.0000x reference)
//
#include <hip/hip_runtime.h>
#include <math.h>

#define BB 32
#define TT 2048
#define DD 1024   // HID == OUT == DV == 1024
#define HF 512    // OUT/2

#define QKS 32            // k-split chunks for query projection
#define QCH (DD / QKS)    // 32 h per chunk

#define CHK 16            // t-rows per fused score+context chunk
#define NCH (TT / CHK)    // 128 chunks per batch row

// ---------------------------------------------------------------------------
__device__ __forceinline__ float tanh_fast(float x) {
    float e = __expf(2.0f * x);
    return 1.0f - 2.0f / (e + 1.0f);
}

// ---------------------------------------------------------------------------
// blocks 0..3: w[d]=sum_j W1[d,j]*W2[j]; block 4: cbias; blocks 5..132: qpart
__global__ void __launch_bounds__(256) prep_query_kernel(
        const float* __restrict__ hidden, const float* __restrict__ Wq,
        const float* __restrict__ W1, const float* __restrict__ b1,
        const float* __restrict__ W2, const float* __restrict__ b2,
        float* __restrict__ w, float* __restrict__ cbias,
        float* __restrict__ qpart) {
    __shared__ float smem[BB * QCH];   // 4 KB
    int bx  = blockIdx.x;
    int tid = threadIdx.x;

    if (bx < 4) {                                   // ---- w = W1 @ W2
        int d = bx * 256 + tid;
        const float* row = W1 + (size_t)d * HF;
        float acc = 0.0f;
        #pragma unroll 4
        for (int j = 0; j < HF; j += 4) {
            float4 a = *(const float4*)(row + j);
            float4 b = *(const float4*)(W2 + j);
            acc += a.x * b.x + a.y * b.y + a.z * b.z + a.w * b.w;
        }
        w[d] = acc;
        return;
    }
    if (bx == 4) {                                  // ---- cbias
        float s = b1[tid] * W2[tid] + b1[tid + 256] * W2[tid + 256];
        smem[tid] = s;
        __syncthreads();
        for (int off = 128; off; off >>= 1) {
            if (tid < off) smem[tid] += smem[tid + off];
            __syncthreads();
        }
        if (tid == 0) cbias[0] = smem[0] + b2[0];
        return;
    }
    // ---- query partial
    int idx = bx - 5, otile = idx & 3, ks = idx >> 2;
    int o = otile * 256 + tid, h0 = ks * QCH;
    { int r = tid >> 3, c4 = (tid & 7) << 2;
      *(float4*)&smem[r * QCH + c4] = *(const float4*)&hidden[(size_t)r * DD + h0 + c4]; }
    __syncthreads();
    float acc[BB];
    #pragma unroll
    for (int b = 0; b < BB; ++b) acc[b] = 0.0f;
    for (int h = 0; h < QCH; ++h) {
        float wv = Wq[(size_t)(h0 + h) * DD + o];
        #pragma unroll
        for (int b = 0; b < BB; ++b)
            acc[b] = fmaf(smem[b * QCH + h], wv, acc[b]);
    }
    #pragma unroll
    for (int b = 0; b < BB; ++b)
        qpart[((size_t)ks * BB + b) * DD + o] = acc[b];
}

// ---------------------------------------------------------------------------
// query[b,o] = bq[o] + sum_ks qpart[ks][b][o]
__global__ void __launch_bounds__(256) qreduce_kernel(
        const float* __restrict__ qpart, const float* __restrict__ bq,
        float* __restrict__ query) {
    int i = blockIdx.x * 256 + threadIdx.x;   // grid 128
    int o = i & (DD - 1);
    float acc = bq[o];
    #pragma unroll
    for (int ks = 0; ks < QKS; ++ks)
        acc += qpart[(size_t)ks * (BB * DD) + i];
    query[i] = acc;
}

// ---------------------------------------------------------------------------
// Fused scores + unnormalized context partials for one 16-row chunk.
// 1D grid of BB*NCH = 4096 blocks (2x oversubscribed vs ~2048 resident slots);
// diagonal skew decode breaks the stride-256 block->CU congruence so each
// CU's co-resident blocks span different chunk positions (load balance).
__global__ void __launch_bounds__(256, 8) score_ctx_kernel(
        const float* __restrict__ key, const float* __restrict__ value,
        const float* __restrict__ query, const float* __restrict__ w,
        const float* __restrict__ cb, const int* __restrict__ seq_lens,
        float* __restrict__ escore, float* __restrict__ psum,
        float* __restrict__ partial) {
    int item = blockIdx.x;
    int b    = item >> 7;                   // 128 items per batch row
    int x    = (item + b) & (NCH - 1);      // diagonal skew, bijective per b
    int len  = seq_lens[b];
    int t0   = x * CHK;
    if (t0 >= len) return;

    __shared__ float wsh[DD];
    __shared__ float qsh[DD];
    __shared__ float esm[CHK];
    int tid = threadIdx.x;
    { int i4 = tid * 4;
      *(float4*)&wsh[i4] = *(const float4*)&w[i4];
      *(float4*)&qsh[i4] = *(const float4*)&query[(size_t)b * DD + i4]; }
    __syncthreads();

    int wave = tid >> 6, lane = tid & 63;
    float c0 = cb[0];

    // ---- scores: wave handles rows r = tt*4 + wave
    #pragma unroll
    for (int tt = 0; tt < CHK / 4; ++tt) {
        int r = tt * 4 + wave;
        int t = t0 + r;
        float e = 0.0f;
        if (t < len) {
            const float* krow = key + ((size_t)b * TT + t) * DD;
            float acc = 0.0f;
            #pragma unroll
            for (int kb = 0; kb < 4; ++kb) {
                int d = kb * 256 + lane * 4;
                float4 kv = *(const float4*)(krow + d);
                float4 qv = *(const float4*)&qsh[d];
                float4 wv = *(const float4*)&wsh[d];
                acc += tanh_fast(kv.x + qv.x) * wv.x;
                acc += tanh_fast(kv.y + qv.y) * wv.y;
                acc += tanh_fast(kv.z + qv.z) * wv.z;
                acc += tanh_fast(kv.w + qv.w) * wv.w;
            }
            #pragma unroll
            for (int off = 32; off; off >>= 1) acc += __shfl_down(acc, off);
            if (lane == 0) e = __expf(acc + c0);
        }
        if (lane == 0) esm[r] = e;
    }
    __syncthreads();

    // ---- escore + psum (fixed order, deterministic)
    if (tid < CHK) escore[(size_t)b * TT + t0 + tid] = esm[tid];
    if (tid == 0) {
        float s = 0.0f;
        #pragma unroll
        for (int i = 0; i < CHK; ++i) s += esm[i];
        psum[b * NCH + x] = s;
    }

    // ---- PV: unnormalized partial
    int d4 = tid * 4;
    int tend = min(t0 + CHK, len);
    const float* vbase = value + (size_t)b * TT * DD + d4;
    float4 acc = {0.0f, 0.0f, 0.0f, 0.0f};
    for (int t = t0; t < tend; ++t) {
        float a = esm[t - t0];
        float4 vv = *(const float4*)(vbase + (size_t)t * DD);
        acc.x = fmaf(a, vv.x, acc.x);
        acc.y = fmaf(a, vv.y, acc.y);
        acc.z = fmaf(a, vv.z, acc.z);
        acc.w = fmaf(a, vv.w, acc.w);
    }
    *(float4*)&partial[((size_t)(b * NCH + x)) * DD + d4] = acc;
}

// ---------------------------------------------------------------------------
// blocks 0..127 : ctx[b,d] = (sum live chunks partial)/S
// blocks 128..191: attn[b,t] = (t<len) ? escore/S : 0
__global__ void __launch_bounds__(256) finalize_kernel(
        const float* __restrict__ partial, const float* __restrict__ escore,
        const float* __restrict__ psum, const int* __restrict__ seq_lens,
        float* __restrict__ ctx, float* __restrict__ attn) {
    __shared__ float red[NCH];
    int bx = blockIdx.x, tid = threadIdx.x;
    int b  = (bx < 128) ? (bx >> 2) : (((bx - 128) * 1024) >> 11);
    int len = seq_lens[b];
    int nch = (len + CHK - 1) / CHK;

    // parallel fixed-order-per-thread reduce of psum[b, 0..nch)
    if (tid < NCH) red[tid] = (tid < nch) ? psum[b * NCH + tid] : 0.0f;
    __syncthreads();
    for (int off = NCH / 2; off; off >>= 1) {
        if (tid < off) red[tid] += red[tid + off];
        __syncthreads();
    }
    float Sinv = 1.0f / red[0];

    if (bx < 128) {
        int d = (bx & 3) * 256 + tid;
        float acc = 0.0f;
        for (int c = 0; c < nch; ++c)
            acc += partial[((size_t)(b * NCH + c)) * DD + d];
        ctx[(size_t)b * DD + d] = acc * Sinv;
    } else {
        int idx = (bx - 128) * 1024 + tid * 4;    // 64 blocks x 1024 elems
        int t   = idx & (TT - 1);
        float4 e = *(const float4*)&escore[(size_t)b * TT + t];
        float4 o;
        o.x = (t + 0 < len) ? e.x * Sinv : 0.0f;
        o.y = (t + 1 < len) ? e.y * Sinv : 0.0f;
        o.z = (t + 2 < len) ? e.z * Sinv : 0.0f;
        o.w = (t + 3 < len) ? e.w * Sinv : 0.0f;
        *(float4*)&attn[(size_t)b * TT + t] = o;
    }
}

// ---------------------------------------------------------------------------
extern "C" void kernel_launch(void* const* d_in, const int* in_sizes, int n_in,
                              void* d_out, int out_size, void* d_ws, size_t ws_size,
                              hipStream_t stream) {
    const float* hidden   = (const float*)d_in[0];
    const float* key      = (const float*)d_in[1];
    const float* value    = (const float*)d_in[2];
    const int*   seq_lens = (const int*)  d_in[3];
    const float* Wq       = (const float*)d_in[4];
    const float* bq       = (const float*)d_in[5];
    const float* W1       = (const float*)d_in[6];
    const float* b1       = (const float*)d_in[7];
    const float* W2       = (const float*)d_in[8];
    const float* b2       = (const float*)d_in[9];

    float* out  = (float*)d_out;
    float* ctx  = out;                 // [32*1024]
    float* attn = out + BB * DD;       // [32*2048]

    float* ws      = (float*)d_ws;
    float* w       = ws;                               // 1024
    float* cb      = ws + 1024;                        // 1 (padded)
    float* query   = ws + 2048;                        // 32768
    float* qpart   = query + BB * DD;                  // 32*32*1024
    float* escore  = qpart + (size_t)QKS * BB * DD;    // 65536
    float* psum    = escore + BB * TT;                 // 32*128 = 4096
    float* partial = psum + BB * NCH;                  // 32*128*1024 = 16 MB

    prep_query_kernel<<<dim3(5 + 4 * QKS), dim3(256), 0, stream>>>(
        hidden, Wq, W1, b1, W2, b2, w, cb, qpart);
    qreduce_kernel<<<dim3(BB * DD / 256), dim3(256), 0, stream>>>(qpart, bq, query);
    score_ctx_kernel<<<dim3(BB * NCH), dim3(256), 0, stream>>>(
        key, value, query, w, cb, seq_lens, escore, psum, partial);
    finalize_kernel<<<dim3(192), dim3(256), 0, stream>>>(
        partial, escore, psum, seq_lens, ctx, attn);
}

// Round 6
// 95.429 us; speedup vs baseline: 1.1617x; 1.1617x over previous
//
#include <hip/hip_runtime.h>
#include <math.h>

#define BB 32
#define TT 2048
#define DD 1024   // HID == OUT == DV == 1024
#define HF 512    // OUT/2

#define QKS 64            // k-split chunks for query projection
#define QCH (DD / QKS)    // 16 h per chunk

#define CHK 32            // t-rows per fused score+context chunk
#define NCH (TT / CHK)    // 64 chunks per batch row

// ---------------------------------------------------------------------------
__device__ __forceinline__ float tanh_fast(float x) {
    float e = __expf(2.0f * x);
    return 1.0f - 2.0f / (e + 1.0f);
}

// ---------------------------------------------------------------------------
// blocks 0..3: w[d]=sum_j W1[d,j]*W2[j]; block 4: cbias; blocks 5..260: qpart
__global__ void __launch_bounds__(256) prep_query_kernel(
        const float* __restrict__ hidden, const float* __restrict__ Wq,
        const float* __restrict__ W1, const float* __restrict__ b1,
        const float* __restrict__ W2, const float* __restrict__ b2,
        float* __restrict__ w, float* __restrict__ cbias,
        float* __restrict__ qpart) {
    __shared__ float smem[BB * QCH];   // 512 floats
    int bx  = blockIdx.x;
    int tid = threadIdx.x;

    if (bx < 4) {                                   // ---- w = W1 @ W2
        int d = bx * 256 + tid;
        const float* row = W1 + (size_t)d * HF;
        float acc = 0.0f;
        #pragma unroll 8
        for (int j = 0; j < HF; j += 4) {
            float4 a = *(const float4*)(row + j);
            float4 b = *(const float4*)(W2 + j);
            acc += a.x * b.x + a.y * b.y + a.z * b.z + a.w * b.w;
        }
        w[d] = acc;
        return;
    }
    if (bx == 4) {                                  // ---- cbias
        __shared__ float red[256];
        float s = b1[tid] * W2[tid] + b1[tid + 256] * W2[tid + 256];
        red[tid] = s;
        __syncthreads();
        for (int off = 128; off; off >>= 1) {
            if (tid < off) red[tid] += red[tid + off];
            __syncthreads();
        }
        if (tid == 0) cbias[0] = red[0] + b2[0];
        return;
    }
    // ---- query partial: idx -> (otile, ks)
    int idx = bx - 5, otile = idx & 3, ks = idx >> 2;
    int o = otile * 256 + tid, h0 = ks * QCH;
    if (tid < 128) {   // 128 threads x float4 = 512 floats = 32 rows x 16 h
        int r = tid >> 2, c4 = (tid & 3) << 2;
        *(float4*)&smem[r * QCH + c4] = *(const float4*)&hidden[(size_t)r * DD + h0 + c4];
    }
    __syncthreads();

    // 16 independent weight loads issued up-front, then FMA sweep
    float wv[QCH];
    #pragma unroll
    for (int h = 0; h < QCH; ++h)
        wv[h] = Wq[(size_t)(h0 + h) * DD + o];

    float acc[BB];
    #pragma unroll
    for (int b = 0; b < BB; ++b) acc[b] = 0.0f;
    #pragma unroll
    for (int h = 0; h < QCH; ++h) {
        #pragma unroll
        for (int b = 0; b < BB; ++b)
            acc[b] = fmaf(smem[b * QCH + h], wv[h], acc[b]);
    }
    #pragma unroll
    for (int b = 0; b < BB; ++b)
        qpart[((size_t)ks * BB + b) * DD + o] = acc[b];
}

// ---------------------------------------------------------------------------
// query[b,o] = bq[o] + sum_ks qpart[ks][b][o]
__global__ void __launch_bounds__(256) qreduce_kernel(
        const float* __restrict__ qpart, const float* __restrict__ bq,
        float* __restrict__ query) {
    int i = blockIdx.x * 256 + threadIdx.x;   // grid 128
    int o = i & (DD - 1);
    float a0 = bq[o], a1 = 0.0f, a2 = 0.0f, a3 = 0.0f;
    #pragma unroll 4
    for (int ks = 0; ks < QKS; ks += 4) {
        a0 += qpart[(size_t)(ks + 0) * (BB * DD) + i];
        a1 += qpart[(size_t)(ks + 1) * (BB * DD) + i];
        a2 += qpart[(size_t)(ks + 2) * (BB * DD) + i];
        a3 += qpart[(size_t)(ks + 3) * (BB * DD) + i];
    }
    query[i] = (a0 + a1) + (a2 + a3);
}

// ---------------------------------------------------------------------------
// Fused scores + unnormalized context partials for one 32-row chunk.
// 1D grid of NCH*BB = 2048 blocks (exactly ~8/CU). Decode b = item & 31 so
// consecutive blocks span batches (uniform len mix per CU/XCD); low chunk
// indices (always live) dispatch first, mostly-dead high chunks flush last.
__global__ void __launch_bounds__(256, 8) score_ctx_kernel(
        const float* __restrict__ key, const float* __restrict__ value,
        const float* __restrict__ query, const float* __restrict__ w,
        const float* __restrict__ cb, const int* __restrict__ seq_lens,
        float* __restrict__ escore, float* __restrict__ psum,
        float* __restrict__ partial) {
    int item = blockIdx.x;
    int b    = item & (BB - 1);
    int x    = item >> 5;
    int len  = seq_lens[b];
    int t0   = x * CHK;
    if (t0 >= len) return;

    __shared__ float wsh[DD];
    __shared__ float qsh[DD];
    __shared__ float esm[CHK];
    int tid = threadIdx.x;
    { int i4 = tid * 4;
      *(float4*)&wsh[i4] = *(const float4*)&w[i4];
      *(float4*)&qsh[i4] = *(const float4*)&query[(size_t)b * DD + i4]; }
    __syncthreads();

    int wave = tid >> 6, lane = tid & 63;
    float c0 = cb[0];

    // ---- scores: wave handles rows r = tt*4 + wave
    #pragma unroll 4
    for (int tt = 0; tt < CHK / 4; ++tt) {
        int r = tt * 4 + wave;
        int t = t0 + r;
        float e = 0.0f;
        if (t < len) {
            const float* krow = key + ((size_t)b * TT + t) * DD;
            float acc = 0.0f;
            #pragma unroll
            for (int kb = 0; kb < 4; ++kb) {
                int d = kb * 256 + lane * 4;
                float4 kv = *(const float4*)(krow + d);
                float4 qv = *(const float4*)&qsh[d];
                float4 wv = *(const float4*)&wsh[d];
                acc += tanh_fast(kv.x + qv.x) * wv.x;
                acc += tanh_fast(kv.y + qv.y) * wv.y;
                acc += tanh_fast(kv.z + qv.z) * wv.z;
                acc += tanh_fast(kv.w + qv.w) * wv.w;
            }
            #pragma unroll
            for (int off = 32; off; off >>= 1) acc += __shfl_down(acc, off);
            if (lane == 0) e = __expf(acc + c0);
        }
        if (lane == 0) esm[r] = e;
    }
    __syncthreads();

    // ---- escore + psum (fixed order, deterministic)
    if (tid < CHK) escore[(size_t)b * TT + t0 + tid] = esm[tid];
    if (tid == 0) {
        float s = 0.0f;
        #pragma unroll
        for (int i = 0; i < CHK; ++i) s += esm[i];
        psum[b * NCH + x] = s;
    }

    // ---- PV: unnormalized partial, two independent accumulator chains
    int d4 = tid * 4;
    int tend = min(t0 + CHK, len);
    const float* vbase = value + (size_t)b * TT * DD + d4;
    float4 acc0 = {0.0f, 0.0f, 0.0f, 0.0f};
    float4 acc1 = {0.0f, 0.0f, 0.0f, 0.0f};
    int t = t0;
    for (; t + 1 < tend; t += 2) {
        float a0 = esm[t - t0], a1 = esm[t - t0 + 1];
        float4 v0 = *(const float4*)(vbase + (size_t)t * DD);
        float4 v1 = *(const float4*)(vbase + (size_t)(t + 1) * DD);
        acc0.x = fmaf(a0, v0.x, acc0.x);  acc1.x = fmaf(a1, v1.x, acc1.x);
        acc0.y = fmaf(a0, v0.y, acc0.y);  acc1.y = fmaf(a1, v1.y, acc1.y);
        acc0.z = fmaf(a0, v0.z, acc0.z);  acc1.z = fmaf(a1, v1.z, acc1.z);
        acc0.w = fmaf(a0, v0.w, acc0.w);  acc1.w = fmaf(a1, v1.w, acc1.w);
    }
    if (t < tend) {
        float a0 = esm[t - t0];
        float4 v0 = *(const float4*)(vbase + (size_t)t * DD);
        acc0.x = fmaf(a0, v0.x, acc0.x);
        acc0.y = fmaf(a0, v0.y, acc0.y);
        acc0.z = fmaf(a0, v0.z, acc0.z);
        acc0.w = fmaf(a0, v0.w, acc0.w);
    }
    acc0.x += acc1.x; acc0.y += acc1.y; acc0.z += acc1.z; acc0.w += acc1.w;
    *(float4*)&partial[((size_t)(b * NCH + x)) * DD + d4] = acc0;
}

// ---------------------------------------------------------------------------
// blocks 0..127 : ctx[b,d] = (sum live chunks partial)/S
// blocks 128..191: attn[b,t] = (t<len) ? escore/S : 0
__global__ void __launch_bounds__(256) finalize_kernel(
        const float* __restrict__ partial, const float* __restrict__ escore,
        const float* __restrict__ psum, const int* __restrict__ seq_lens,
        float* __restrict__ ctx, float* __restrict__ attn) {
    __shared__ float red[NCH];
    int bx = blockIdx.x, tid = threadIdx.x;
    int b  = (bx < 128) ? (bx >> 2) : (((bx - 128) * 1024) >> 11);
    int len = seq_lens[b];
    int nch = (len + CHK - 1) / CHK;

    if (tid < NCH) red[tid] = (tid < nch) ? psum[b * NCH + tid] : 0.0f;
    __syncthreads();
    for (int off = NCH / 2; off; off >>= 1) {
        if (tid < off) red[tid] += red[tid + off];
        __syncthreads();
    }
    float Sinv = 1.0f / red[0];

    if (bx < 128) {
        int d = (bx & 3) * 256 + tid;
        const float* pb = partial + (size_t)b * NCH * DD + d;
        float a0 = 0.0f, a1 = 0.0f, a2 = 0.0f, a3 = 0.0f;
        int c = 0;
        for (; c + 3 < nch; c += 4) {
            a0 += pb[(size_t)(c + 0) * DD];
            a1 += pb[(size_t)(c + 1) * DD];
            a2 += pb[(size_t)(c + 2) * DD];
            a3 += pb[(size_t)(c + 3) * DD];
        }
        for (; c < nch; ++c) a0 += pb[(size_t)c * DD];
        ctx[(size_t)b * DD + d] = ((a0 + a1) + (a2 + a3)) * Sinv;
    } else {
        int idx = (bx - 128) * 1024 + tid * 4;    // 64 blocks x 1024 elems
        int t   = idx & (TT - 1);
        float4 e = *(const float4*)&escore[(size_t)b * TT + t];
        float4 o;
        o.x = (t + 0 < len) ? e.x * Sinv : 0.0f;
        o.y = (t + 1 < len) ? e.y * Sinv : 0.0f;
        o.z = (t + 2 < len) ? e.z * Sinv : 0.0f;
        o.w = (t + 3 < len) ? e.w * Sinv : 0.0f;
        *(float4*)&attn[(size_t)b * TT + t] = o;
    }
}

// ---------------------------------------------------------------------------
extern "C" void kernel_launch(void* const* d_in, const int* in_sizes, int n_in,
                              void* d_out, int out_size, void* d_ws, size_t ws_size,
                              hipStream_t stream) {
    const float* hidden   = (const float*)d_in[0];
    const float* key      = (const float*)d_in[1];
    const float* value    = (const float*)d_in[2];
    const int*   seq_lens = (const int*)  d_in[3];
    const float* Wq       = (const float*)d_in[4];
    const float* bq       = (const float*)d_in[5];
    const float* W1       = (const float*)d_in[6];
    const float* b1       = (const float*)d_in[7];
    const float* W2       = (const float*)d_in[8];
    const float* b2       = (const float*)d_in[9];

    float* out  = (float*)d_out;
    float* ctx  = out;                 // [32*1024]
    float* attn = out + BB * DD;       // [32*2048]

    float* ws      = (float*)d_ws;
    float* w       = ws;                               // 1024
    float* cb      = ws + 1024;                        // 1 (padded)
    float* query   = ws + 2048;                        // 32768
    float* qpart   = query + BB * DD;                  // 64*32*1024 = 2 M floats
    float* escore  = qpart + (size_t)QKS * BB * DD;    // 65536
    float* psum    = escore + BB * TT;                 // 32*64 = 2048
    float* partial = psum + BB * NCH;                  // 32*64*1024 = 8 MB

    prep_query_kernel<<<dim3(5 + 4 * QKS), dim3(256), 0, stream>>>(
        hidden, Wq, W1, b1, W2, b2, w, cb, qpart);
    qreduce_kernel<<<dim3(BB * DD / 256), dim3(256), 0, stream>>>(qpart, bq, query);
    score_ctx_kernel<<<dim3(BB * NCH), dim3(256), 0, stream>>>(
        key, value, query, w, cb, seq_lens, escore, psum, partial);
    finalize_kernel<<<dim3(192), dim3(256), 0, stream>>>(
        partial, escore, psum, seq_lens, ctx, attn);
}

// Round 7
// 85.362 us; speedup vs baseline: 1.2987x; 1.1179x over previous
//
#include <hip/hip_runtime.h>
#include <math.h>

#define BB 32
#define TT 2048
#define DD 1024   // HID == OUT == DV == 1024
#define HF 512    // OUT/2

#define QKS 64            // k-split chunks for query projection
#define QCH (DD / QKS)    // 16 h per chunk

#define CHK 32            // t-rows per fused score+context chunk
#define NCH (TT / CHK)    // 64 chunks per batch row

// ---------------------------------------------------------------------------
__device__ __forceinline__ float tanh_fast(float x) {
    float e = __expf(2.0f * x);
    return 1.0f - 2.0f * __builtin_amdgcn_rcpf(e + 1.0f);
}

// ---------------------------------------------------------------------------
// blocks 0..3: w[d]=sum_j W1[d,j]*W2[j]; block 4: cbias; blocks 5..260: qpart
__global__ void __launch_bounds__(256) prep_query_kernel(
        const float* __restrict__ hidden, const float* __restrict__ Wq,
        const float* __restrict__ W1, const float* __restrict__ b1,
        const float* __restrict__ W2, const float* __restrict__ b2,
        float* __restrict__ w, float* __restrict__ cbias,
        float* __restrict__ qpart) {
    __shared__ float smem[BB * QCH];   // 512 floats
    int bx  = blockIdx.x;
    int tid = threadIdx.x;

    if (bx < 4) {                                   // ---- w = W1 @ W2
        int d = bx * 256 + tid;
        const float* row = W1 + (size_t)d * HF;
        float acc = 0.0f;
        #pragma unroll 8
        for (int j = 0; j < HF; j += 4) {
            float4 a = *(const float4*)(row + j);
            float4 b = *(const float4*)(W2 + j);
            acc += a.x * b.x + a.y * b.y + a.z * b.z + a.w * b.w;
        }
        w[d] = acc;
        return;
    }
    if (bx == 4) {                                  // ---- cbias
        __shared__ float red[256];
        float s = b1[tid] * W2[tid] + b1[tid + 256] * W2[tid + 256];
        red[tid] = s;
        __syncthreads();
        for (int off = 128; off; off >>= 1) {
            if (tid < off) red[tid] += red[tid + off];
            __syncthreads();
        }
        if (tid == 0) cbias[0] = red[0] + b2[0];
        return;
    }
    // ---- query partial: idx -> (otile, ks)
    int idx = bx - 5, otile = idx & 3, ks = idx >> 2;
    int o = otile * 256 + tid, h0 = ks * QCH;
    if (tid < 128) {   // 128 threads x float4 = 512 floats = 32 rows x 16 h
        int r = tid >> 2, c4 = (tid & 3) << 2;
        *(float4*)&smem[r * QCH + c4] = *(const float4*)&hidden[(size_t)r * DD + h0 + c4];
    }
    __syncthreads();

    float wv[QCH];
    #pragma unroll
    for (int h = 0; h < QCH; ++h)
        wv[h] = Wq[(size_t)(h0 + h) * DD + o];

    float acc[BB];
    #pragma unroll
    for (int b = 0; b < BB; ++b) acc[b] = 0.0f;
    #pragma unroll
    for (int h = 0; h < QCH; ++h) {
        #pragma unroll
        for (int b = 0; b < BB; ++b)
            acc[b] = fmaf(smem[b * QCH + h], wv[h], acc[b]);
    }
    #pragma unroll
    for (int b = 0; b < BB; ++b)
        qpart[((size_t)ks * BB + b) * DD + o] = acc[b];
}

// ---------------------------------------------------------------------------
// query[b,o] = bq[o] + sum_ks qpart[ks][b][o]
// 256 blocks (1/CU): each block 128 elements x 2 ks-halves; LDS combine.
__global__ void __launch_bounds__(256) qreduce_kernel(
        const float* __restrict__ qpart, const float* __restrict__ bq,
        float* __restrict__ query) {
    __shared__ float part[256];
    int bx = blockIdx.x, tid = threadIdx.x;
    int e = tid & 127, g = tid >> 7;
    int i = bx * 128 + e;
    int ks0 = g * (QKS / 2);
    float a0 = 0.0f, a1 = 0.0f, a2 = 0.0f, a3 = 0.0f;
    #pragma unroll 8
    for (int k = 0; k < QKS / 2; k += 4) {
        size_t base = (size_t)(ks0 + k) * (BB * DD) + i;
        a0 += qpart[base];
        a1 += qpart[base + (size_t)(BB * DD)];
        a2 += qpart[base + 2 * (size_t)(BB * DD)];
        a3 += qpart[base + 3 * (size_t)(BB * DD)];
    }
    part[tid] = (a0 + a1) + (a2 + a3);
    __syncthreads();
    if (g == 0) query[i] = bq[i & (DD - 1)] + part[tid] + part[tid + 128];
}

// ---------------------------------------------------------------------------
// Fused scores + unnormalized context partials for one 32-row chunk.
// Score loop: register double-buffered key rows (8 float4 in flight/wave).
// Dead rows (t>=len) are clamped on load and zeroed in esm, so PV runs
// branch-free over all 32 rows (dead rows weighted 0).
__global__ void __launch_bounds__(256, 6) score_ctx_kernel(
        const float* __restrict__ key, const float* __restrict__ value,
        const float* __restrict__ query, const float* __restrict__ w,
        const float* __restrict__ cb, const int* __restrict__ seq_lens,
        float* __restrict__ escore, float* __restrict__ psum,
        float* __restrict__ partial) {
    int item = blockIdx.x;
    int b    = item & (BB - 1);
    int x    = item >> 5;
    int len  = seq_lens[b];
    int t0   = x * CHK;
    if (t0 >= len) return;

    __shared__ float wsh[DD];
    __shared__ float qsh[DD];
    __shared__ float esm[CHK];
    int tid = threadIdx.x;
    { int i4 = tid * 4;
      *(float4*)&wsh[i4] = *(const float4*)&w[i4];
      *(float4*)&qsh[i4] = *(const float4*)&query[(size_t)b * DD + i4]; }
    __syncthreads();

    int wave = tid >> 6, lane = tid & 63;
    float c0 = cb[0];
    const float* kb0 = key + (size_t)b * TT * DD;

    // ---- scores: wave handles rows j*4 + wave, software pipelined
    float4 kreg[2][4];
    {
        int t = min(t0 + wave, len - 1);
        const float* kr = kb0 + (size_t)t * DD;
        #pragma unroll
        for (int s = 0; s < 4; ++s)
            kreg[0][s] = *(const float4*)(kr + s * 256 + lane * 4);
    }
    #pragma unroll
    for (int j = 0; j < 8; ++j) {
        if (j < 7) {
            int t = min(t0 + (j + 1) * 4 + wave, len - 1);
            const float* kr = kb0 + (size_t)t * DD;
            #pragma unroll
            for (int s = 0; s < 4; ++s)
                kreg[(j + 1) & 1][s] = *(const float4*)(kr + s * 256 + lane * 4);
        }
        float acc = 0.0f;
        #pragma unroll
        for (int s = 0; s < 4; ++s) {
            int d = s * 256 + lane * 4;
            float4 kv = kreg[j & 1][s];
            float4 qv = *(const float4*)&qsh[d];
            float4 wv = *(const float4*)&wsh[d];
            acc += tanh_fast(kv.x + qv.x) * wv.x;
            acc += tanh_fast(kv.y + qv.y) * wv.y;
            acc += tanh_fast(kv.z + qv.z) * wv.z;
            acc += tanh_fast(kv.w + qv.w) * wv.w;
        }
        #pragma unroll
        for (int off = 32; off; off >>= 1) acc += __shfl_down(acc, off);
        if (lane == 0) {
            int t = t0 + j * 4 + wave;
            esm[j * 4 + wave] = (t < len) ? __expf(acc + c0) : 0.0f;
        }
    }
    __syncthreads();

    // ---- escore + psum (fixed order, deterministic)
    if (tid < CHK) escore[(size_t)b * TT + t0 + tid] = esm[tid];
    if (tid == 0) {
        float s = 0.0f;
        #pragma unroll
        for (int i = 0; i < CHK; ++i) s += esm[i];
        psum[b * NCH + x] = s;
    }

    // ---- PV: 4 accumulator chains, branch-free over all 32 rows
    int d4 = tid * 4;
    const float* vbase = value + (size_t)b * TT * DD + d4;
    float4 A0 = {0.0f, 0.0f, 0.0f, 0.0f};
    float4 A1 = A0, A2 = A0, A3 = A0;
    #pragma unroll 2
    for (int tt = 0; tt < CHK; tt += 4) {
        float e0 = esm[tt], e1 = esm[tt + 1], e2 = esm[tt + 2], e3 = esm[tt + 3];
        float4 v0 = *(const float4*)(vbase + (size_t)(t0 + tt    ) * DD);
        float4 v1 = *(const float4*)(vbase + (size_t)(t0 + tt + 1) * DD);
        float4 v2 = *(const float4*)(vbase + (size_t)(t0 + tt + 2) * DD);
        float4 v3 = *(const float4*)(vbase + (size_t)(t0 + tt + 3) * DD);
        A0.x = fmaf(e0, v0.x, A0.x); A0.y = fmaf(e0, v0.y, A0.y);
        A0.z = fmaf(e0, v0.z, A0.z); A0.w = fmaf(e0, v0.w, A0.w);
        A1.x = fmaf(e1, v1.x, A1.x); A1.y = fmaf(e1, v1.y, A1.y);
        A1.z = fmaf(e1, v1.z, A1.z); A1.w = fmaf(e1, v1.w, A1.w);
        A2.x = fmaf(e2, v2.x, A2.x); A2.y = fmaf(e2, v2.y, A2.y);
        A2.z = fmaf(e2, v2.z, A2.z); A2.w = fmaf(e2, v2.w, A2.w);
        A3.x = fmaf(e3, v3.x, A3.x); A3.y = fmaf(e3, v3.y, A3.y);
        A3.z = fmaf(e3, v3.z, A3.z); A3.w = fmaf(e3, v3.w, A3.w);
    }
    float4 R;
    R.x = (A0.x + A1.x) + (A2.x + A3.x);
    R.y = (A0.y + A1.y) + (A2.y + A3.y);
    R.z = (A0.z + A1.z) + (A2.z + A3.z);
    R.w = (A0.w + A1.w) + (A2.w + A3.w);
    *(float4*)&partial[((size_t)(b * NCH + x)) * DD + d4] = R;
}

// ---------------------------------------------------------------------------
// blocks 0..255 : ctx[b,d] = (sum live chunks partial)/S   (b=bx>>3, 128-d slice)
// blocks 256..319: attn[b,t] = (t<len) ? escore/S : 0
__global__ void __launch_bounds__(256) finalize_kernel(
        const float* __restrict__ partial, const float* __restrict__ escore,
        const float* __restrict__ psum, const int* __restrict__ seq_lens,
        float* __restrict__ ctx, float* __restrict__ attn) {
    __shared__ float red[NCH];
    __shared__ float part[256];
    int bx = blockIdx.x, tid = threadIdx.x;
    int b  = (bx < 256) ? (bx >> 3) : ((bx - 256) >> 1);
    int len = seq_lens[b];
    int nch = (len + CHK - 1) / CHK;

    if (tid < NCH) red[tid] = (tid < nch) ? psum[b * NCH + tid] : 0.0f;
    __syncthreads();
    #pragma unroll
    for (int off = NCH / 2; off; off >>= 1) {
        if (tid < off) red[tid] += red[tid + off];
        __syncthreads();
    }
    float Sinv = 1.0f / red[0];

    if (bx < 256) {
        int e = tid & 127, g = tid >> 7;
        int d = (bx & 7) * 128 + e;
        const float* pb = partial + (size_t)b * NCH * DD + d;
        int cbeg = g * 32, cend = min(nch, cbeg + 32);
        float a0 = 0.0f, a1 = 0.0f, a2 = 0.0f, a3 = 0.0f;
        int c = cbeg;
        for (; c + 3 < cend; c += 4) {
            a0 += pb[(size_t)(c + 0) * DD];
            a1 += pb[(size_t)(c + 1) * DD];
            a2 += pb[(size_t)(c + 2) * DD];
            a3 += pb[(size_t)(c + 3) * DD];
        }
        for (; c < cend; ++c) a0 += pb[(size_t)c * DD];
        part[tid] = (a0 + a1) + (a2 + a3);
        __syncthreads();
        if (g == 0) ctx[(size_t)b * DD + d] = (part[tid] + part[tid + 128]) * Sinv;
    } else {
        int idx = (bx - 256) * 1024 + tid * 4;    // 64 blocks x 1024 elems
        int t   = idx & (TT - 1);
        float4 e4 = *(const float4*)&escore[(size_t)b * TT + t];
        float4 o;
        o.x = (t + 0 < len) ? e4.x * Sinv : 0.0f;
        o.y = (t + 1 < len) ? e4.y * Sinv : 0.0f;
        o.z = (t + 2 < len) ? e4.z * Sinv : 0.0f;
        o.w = (t + 3 < len) ? e4.w * Sinv : 0.0f;
        *(float4*)&attn[(size_t)b * TT + t] = o;
    }
}

// ---------------------------------------------------------------------------
extern "C" void kernel_launch(void* const* d_in, const int* in_sizes, int n_in,
                              void* d_out, int out_size, void* d_ws, size_t ws_size,
                              hipStream_t stream) {
    const float* hidden   = (const float*)d_in[0];
    const float* key      = (const float*)d_in[1];
    const float* value    = (const float*)d_in[2];
    const int*   seq_lens = (const int*)  d_in[3];
    const float* Wq       = (const float*)d_in[4];
    const float* bq       = (const float*)d_in[5];
    const float* W1       = (const float*)d_in[6];
    const float* b1       = (const float*)d_in[7];
    const float* W2       = (const float*)d_in[8];
    const float* b2       = (const float*)d_in[9];

    float* out  = (float*)d_out;
    float* ctx  = out;                 // [32*1024]
    float* attn = out + BB * DD;       // [32*2048]

    float* ws      = (float*)d_ws;
    float* w       = ws;                               // 1024
    float* cb      = ws + 1024;                        // 1 (padded)
    float* query   = ws + 2048;                        // 32768
    float* qpart   = query + BB * DD;                  // 64*32*1024 = 2 M floats
    float* escore  = qpart + (size_t)QKS * BB * DD;    // 65536
    float* psum    = escore + BB * TT;                 // 32*64 = 2048
    float* partial = psum + BB * NCH;                  // 32*64*1024 = 8 MB

    prep_query_kernel<<<dim3(5 + 4 * QKS), dim3(256), 0, stream>>>(
        hidden, Wq, W1, b1, W2, b2, w, cb, qpart);
    qreduce_kernel<<<dim3(BB * DD / 128), dim3(256), 0, stream>>>(qpart, bq, query);
    score_ctx_kernel<<<dim3(BB * NCH), dim3(256), 0, stream>>>(
        key, value, query, w, cb, seq_lens, escore, psum, partial);
    finalize_kernel<<<dim3(320), dim3(256), 0, stream>>>(
        partial, escore, psum, seq_lens, ctx, attn);
}